// Round 3
// baseline (295.694 us; speedup 1.0000x reference)
//
#include <hip/hip_runtime.h>

typedef __attribute__((ext_vector_type(8))) __bf16 bf16x8;
typedef __attribute__((ext_vector_type(4))) float f32x4;

__device__ __forceinline__ float bf2f(unsigned int u) {
    return __uint_as_float(u << 16);
}
__device__ __forceinline__ unsigned short f2bf(float f) {
    unsigned int x = __float_as_uint(f);
    return (unsigned short)((x + 0x7fffu + ((x >> 16) & 1u)) >> 16);
}

// pack 2 bf16 products: low = bf16(e_lo*r_lo), high = bf16(e_hi*r_hi)
__device__ __forceinline__ unsigned int mulpack(unsigned int e, unsigned int r) {
    float e0 = __uint_as_float(e << 16);
    float e1 = __uint_as_float(e & 0xffff0000u);
    float r0 = __uint_as_float(r << 16);
    float r1 = __uint_as_float(r & 0xffff0000u);
    float p0 = e0 * r0;
    float p1 = e1 * r1;
    unsigned int out;
    asm("v_cvt_pk_bf16_f32 %0, %1, %2" : "=v"(out) : "v"(p0), "v"(p1));
    return out;
}

// ---------------- cast f32 -> bf16, n4 = n/4 ----------------
__global__ void cast_f32_bf16(const float* __restrict__ in,
                              unsigned short* __restrict__ out, int n4) {
    int i = blockIdx.x * blockDim.x + threadIdx.x;
    if (i >= n4) return;
    float4 v = reinterpret_cast<const float4*>(in)[i];
    ushort4 o;
    o.x = f2bf(v.x); o.y = f2bf(v.y); o.z = f2bf(v.z); o.w = f2bf(v.w);
    reinterpret_cast<ushort4*>(out)[i] = o;
}

// ---------------- gate GEMM (m97 128^2 structure, known-good) ----------------
#define BM 128
#define BN 128
#define BK 64

template <bool GUARD_M, bool BIAS_BF16OUT>
__global__ __launch_bounds__(256, 2) void mfma_gemm_bt(
    const unsigned short* __restrict__ A,
    const unsigned short* __restrict__ Bt,
    const float* __restrict__ bias,
    void* __restrict__ Cout,
    int M, int N, int K) {
    __shared__ __align__(16) unsigned short As[BM * BK];
    __shared__ __align__(16) unsigned short Bs[BN * BK];

    const int tid = threadIdx.x;
    const int lane = tid & 63;
    const int wave = tid >> 6;
    const int nbn = N / BN;
    const int bm0 = (blockIdx.x / nbn) * BM;
    const int bn0 = (blockIdx.x % nbn) * BN;
    const int wr = wave >> 1, wc = wave & 1;

    f32x4 acc[4][4] = {};

    const int srow = wave * 32 + (lane >> 3);
    const int scol = (lane & 7) * 8;

    for (int kb = 0; kb < K; kb += BK) {
#pragma unroll
        for (int i = 0; i < 4; ++i) {
            int row = bm0 + srow + i * 8;
            if (GUARD_M) row = min(row, M - 1);
            const unsigned short* src = A + (size_t)row * K + kb + scol;
            unsigned short* dst = &As[(wave * 32 + i * 8) * BK];
            __builtin_amdgcn_global_load_lds(
                (const __attribute__((address_space(1))) void*)src,
                (__attribute__((address_space(3))) void*)dst, 16, 0, 0);
        }
#pragma unroll
        for (int i = 0; i < 4; ++i) {
            int row = bn0 + srow + i * 8;
            const unsigned short* src = Bt + (size_t)row * K + kb + scol;
            unsigned short* dst = &Bs[(wave * 32 + i * 8) * BK];
            __builtin_amdgcn_global_load_lds(
                (const __attribute__((address_space(1))) void*)src,
                (__attribute__((address_space(3))) void*)dst, 16, 0, 0);
        }
        __syncthreads();

#pragma unroll
        for (int ks = 0; ks < BK / 32; ++ks) {
            const int k0 = ks * 32 + (lane >> 4) * 8;
            bf16x8 av[4], bv[4];
#pragma unroll
            for (int m = 0; m < 4; ++m)
                av[m] = *reinterpret_cast<const bf16x8*>(
                    &As[(wr * 64 + m * 16 + (lane & 15)) * BK + k0]);
#pragma unroll
            for (int n = 0; n < 4; ++n)
                bv[n] = *reinterpret_cast<const bf16x8*>(
                    &Bs[(wc * 64 + n * 16 + (lane & 15)) * BK + k0]);
#pragma unroll
            for (int m = 0; m < 4; ++m)
#pragma unroll
                for (int n = 0; n < 4; ++n)
                    acc[m][n] = __builtin_amdgcn_mfma_f32_16x16x32_bf16(
                        av[m], bv[n], acc[m][n], 0, 0, 0);
        }
        __syncthreads();
    }

#pragma unroll
    for (int m = 0; m < 4; ++m) {
#pragma unroll
        for (int n = 0; n < 4; ++n) {
#pragma unroll
            for (int j = 0; j < 4; ++j) {
                int row = bm0 + wr * 64 + m * 16 + (lane >> 4) * 4 + j;
                int col = bn0 + wc * 64 + n * 16 + (lane & 15);
                if (GUARD_M && row >= M) continue;
                float v = acc[m][n][j];
                if (BIAS_BF16OUT) {
                    v += bias[col];
                    ((unsigned short*)Cout)[(size_t)row * N + col] = f2bf(v);
                } else {
                    ((float*)Cout)[(size_t)row * N + col] = v;
                }
            }
        }
    }
}

// ---------------- main GEMM: 256^2 tile, 8-phase, FUSED A' construction ----------------
// C[65536][2048] = (E[e]*R[r])[er][512] @ E[2048][512]^T, er = e*32+r
// A' never materialized in HBM: per tile, E/R granules loaded from G (L1-hot),
// multiplied in-register, ds_written (swizzled) into the A LDS slots.
// LDS: 2 buffers x {A0,A1,B0,B1} half-tiles of 128rows x 64cols bf16 (16KB each)
#define NT8 8  // K / 64

__global__ __launch_bounds__(512, 2) void gemm256_8ph_fused(
    const unsigned short* __restrict__ G,  // [2080][512]: rows 0..2047=E, 2048..2079=R
    float* __restrict__ C) {
    __shared__ __align__(16) unsigned short lds[65536];  // 128 KiB

    const int tid = threadIdx.x;
    const int lane = tid & 63;
    const int wave = tid >> 6;   // 0..7
    const int wr = wave >> 2;    // 0..1 -> M half
    const int wc = wave & 3;     // 0..3 -> N quarter
    const int laneM = lane & 15;
    const int laneK = (lane >> 4) * 8;
    const int kx = (lane & 7) * 8;

    // XCD-aware swizzle (nwg=2048, divisible by 8)
    const int swz = (blockIdx.x & 7) * 256 + (blockIdx.x >> 3);
    const int bm0 = (swz >> 3) * 256;
    const int bn0 = (swz & 7) * 256;

    // staging coords
    const int kplain = (tid & 7) * 8;            // plain k offset (elements)
    const int sr0 = tid >> 3;                    // row within half-tile (0..63), +64 for rd=1
    const int kswz = kplain ^ ((sr0 & 7) * 8);   // swizzled col (also inverse-swz source for B)

    // B staging via global_load_lds: linear LDS dest, pre-swizzled global source
    auto STAGE_B = [&](int row0, int kb, int slotOff) {
#pragma unroll
        for (int rd = 0; rd < 2; ++rd) {
            const unsigned short* src = G + (size_t)(row0 + sr0 + rd * 64) * 512 + kb + kswz;
            unsigned short* dst = &lds[slotOff + wave * 512 + rd * 4096];  // wave-uniform
            __builtin_amdgcn_global_load_lds(
                (const __attribute__((address_space(1))) void*)src,
                (__attribute__((address_space(3))) void*)dst, 16, 0, 0);
        }
    };
    auto RD = [&](int slotOff, int r, int ks) -> bf16x8 {
        return *reinterpret_cast<const bf16x8*>(
            &lds[slotOff + r * 64 + (((ks * 32) + laneK) ^ kx)]);
    };
    // slots (ushort units): A(P,h)=P*32768+h*8192 ; B(P,h)=P*32768+16384+h*8192

    // A-side fused construction state: 4 granules/thread (2 halves x 2 row-blocks)
    uint4 Eg[4], Rg[4];
    auto ISSUE_A = [&](int kb) {
#pragma unroll
        for (int g = 0; g < 4; ++g) {
            int er = bm0 + (g >> 1) * 128 + (g & 1) * 64 + sr0;
            int e = er >> 5, r = er & 31;
            Eg[g] = *reinterpret_cast<const uint4*>(G + (size_t)e * 512 + kb + kplain);
            Rg[g] = *reinterpret_cast<const uint4*>(G + (size_t)(2048 + r) * 512 + kb + kplain);
        }
    };
    auto WRITE_A = [&](int gbuf) {
#pragma unroll
        for (int g = 0; g < 4; ++g) {
            uint4 o;
            o.x = mulpack(Eg[g].x, Rg[g].x);
            o.y = mulpack(Eg[g].y, Rg[g].y);
            o.z = mulpack(Eg[g].z, Rg[g].z);
            o.w = mulpack(Eg[g].w, Rg[g].w);
            *reinterpret_cast<uint4*>(
                &lds[gbuf * 32768 + (g >> 1) * 8192 + ((g & 1) * 64 + sr0) * 64 + kswz]) = o;
        }
    };

    f32x4 acc[8][4] = {};
    bf16x8 av[4][2], bv0[2][2], bv1[2][2];

    // ===== prologue =====
    ISSUE_A(0);                                            // A(0) E/R loads (compiler-tracked)
    STAGE_B(bn0,       0, 0 * 32768 + 16384 + 0 * 8192);   // (0)B0
    STAGE_B(bn0 + 128, 0, 0 * 32768 + 16384 + 1 * 8192);   // (0)B1
    STAGE_B(bn0,      64, 1 * 32768 + 16384 + 0 * 8192);   // (1)B0
    STAGE_B(bn0 + 128,64, 1 * 32768 + 16384 + 1 * 8192);   // (1)B1
    WRITE_A(0);                                            // compiler waits A-loads, ds_writes
    asm volatile("s_waitcnt vmcnt(4)" ::: "memory");       // (0)B0,B1 complete
    asm volatile("s_waitcnt lgkmcnt(0)" ::: "memory");     // my A(0) ds_writes complete
    __builtin_amdgcn_s_barrier();

#pragma unroll
    for (int t = 0; t < NT8; ++t) {
        const int P = t & 1;
        const int sA = P * 32768 + wr * 8192;
        const int sB = P * 32768 + 16384 + (wc >> 1) * 8192;
        const int rB = (wc & 1) * 64;

        // ===== phase 1: read A-mh0 (8) + B-nh0 (4); issue A(t+1) E/R loads =====
#pragma unroll
        for (int m = 0; m < 4; ++m)
#pragma unroll
            for (int ks = 0; ks < 2; ++ks)
                av[m][ks] = RD(sA, m * 16 + laneM, ks);
#pragma unroll
        for (int n = 0; n < 2; ++n)
#pragma unroll
            for (int ks = 0; ks < 2; ++ks)
                bv0[n][ks] = RD(sB, rB + n * 16 + laneM, ks);
        if (t + 1 < NT8)
            ISSUE_A((t + 1) * 64);
        __builtin_amdgcn_s_barrier();
        asm volatile("s_waitcnt lgkmcnt(0)" ::: "memory");
        __builtin_amdgcn_sched_barrier(0);
        __builtin_amdgcn_s_setprio(1);
#pragma unroll
        for (int ks = 0; ks < 2; ++ks)
#pragma unroll
            for (int m = 0; m < 4; ++m)
#pragma unroll
                for (int n = 0; n < 2; ++n)
                    acc[m][n] = __builtin_amdgcn_mfma_f32_16x16x32_bf16(
                        av[m][ks], bv0[n][ks], acc[m][n], 0, 0, 0);
        __builtin_amdgcn_s_setprio(0);
        __builtin_amdgcn_s_barrier();

        // ===== phase 2: read B-nh1 (4) =====
#pragma unroll
        for (int n = 0; n < 2; ++n)
#pragma unroll
            for (int ks = 0; ks < 2; ++ks)
                bv1[n][ks] = RD(sB, rB + (2 + n) * 16 + laneM, ks);
        __builtin_amdgcn_s_barrier();
        asm volatile("s_waitcnt lgkmcnt(0)" ::: "memory");
        __builtin_amdgcn_sched_barrier(0);
        __builtin_amdgcn_s_setprio(1);
#pragma unroll
        for (int ks = 0; ks < 2; ++ks)
#pragma unroll
            for (int m = 0; m < 4; ++m)
#pragma unroll
                for (int n = 0; n < 2; ++n)
                    acc[m][2 + n] = __builtin_amdgcn_mfma_f32_16x16x32_bf16(
                        av[m][ks], bv1[n][ks], acc[m][2 + n], 0, 0, 0);
        __builtin_amdgcn_s_setprio(0);
        __builtin_amdgcn_s_barrier();

        // ===== phase 3: read A-mh1 (8); stage (t+2)B0; construct+write A(t+1) =====
#pragma unroll
        for (int m = 0; m < 4; ++m)
#pragma unroll
            for (int ks = 0; ks < 2; ++ks)
                av[m][ks] = RD(sA, 64 + m * 16 + laneM, ks);
        if (t + 2 < NT8)
            STAGE_B(bn0, (t + 2) * 64, ((t + 2) & 1) * 32768 + 16384);
        if (t + 1 < NT8)
            WRITE_A((t + 1) & 1);  // compiler inserts vmcnt for Eg/Rg before use
        __builtin_amdgcn_s_barrier();
        asm volatile("s_waitcnt lgkmcnt(0)" ::: "memory");
        __builtin_amdgcn_sched_barrier(0);
        __builtin_amdgcn_s_setprio(1);
#pragma unroll
        for (int ks = 0; ks < 2; ++ks)
#pragma unroll
            for (int m = 0; m < 4; ++m)
#pragma unroll
                for (int n = 0; n < 2; ++n)
                    acc[4 + m][2 + n] = __builtin_amdgcn_mfma_f32_16x16x32_bf16(
                        av[m][ks], bv1[n][ks], acc[4 + m][2 + n], 0, 0, 0);
        __builtin_amdgcn_s_setprio(0);
        __builtin_amdgcn_s_barrier();

        // ===== phase 4: stage (t+2)B1; MFMA Q10 from regs =====
        if (t + 2 < NT8)
            STAGE_B(bn0 + 128, (t + 2) * 64, ((t + 2) & 1) * 32768 + 16384 + 8192);
        __builtin_amdgcn_s_barrier();
        __builtin_amdgcn_s_setprio(1);
#pragma unroll
        for (int ks = 0; ks < 2; ++ks)
#pragma unroll
            for (int m = 0; m < 4; ++m)
#pragma unroll
                for (int n = 0; n < 2; ++n)
                    acc[4 + m][n] = __builtin_amdgcn_mfma_f32_16x16x32_bf16(
                        av[m][ks], bv0[n][ks], acc[4 + m][n], 0, 0, 0);
        __builtin_amdgcn_s_setprio(0);
        if (t < NT8 - 1) {
            if (t == NT8 - 2)
                asm volatile("s_waitcnt vmcnt(0)" ::: "memory");
            else
                asm volatile("s_waitcnt vmcnt(4)" ::: "memory");  // B(t+1) done
            __builtin_amdgcn_s_barrier();
        }
    }

    // epilogue: C/D layout col=lane&15, row=(lane>>4)*4+j
#pragma unroll
    for (int mi = 0; mi < 8; ++mi)
#pragma unroll
        for (int ni = 0; ni < 4; ++ni)
#pragma unroll
            for (int j = 0; j < 4; ++j) {
                int row = bm0 + wr * 128 + mi * 16 + (lane >> 4) * 4 + j;
                int col = bn0 + wc * 64 + ni * 16 + laneM;
                C[(size_t)row * 2048 + col] = acc[mi][ni][j];
            }
}

// ---------------- launcher ----------------
extern "C" void kernel_launch(void* const* d_in, const int* in_sizes, int n_in,
                              void* d_out, int out_size, void* d_ws, size_t ws_size,
                              hipStream_t stream) {
    const float* entities  = (const float*)d_in[0];
    const float* relations = (const float*)d_in[1];
    const float* W         = (const float*)d_in[2];
    const float* b         = (const float*)d_in[3];

    char* ws = (char*)d_ws;
    unsigned short* W_bf = (unsigned short*)ws;
    unsigned short* X_bf = (unsigned short*)(ws + 524288);
    unsigned short* G_bf = (unsigned short*)(ws + 524288 + 2129920);

    cast_f32_bf16<<<1024, 256, 0, stream>>>(entities, X_bf, 262144);
    cast_f32_bf16<<<16, 256, 0, stream>>>(relations, X_bf + 2048 * 512, 4096);
    cast_f32_bf16<<<256, 256, 0, stream>>>(W, W_bf, 65536);

    // gate GEMM: G[2080][512] = X @ W^T + b  (bf16 out)
    mfma_gemm_bt<true, true><<<17 * 4, 256, 0, stream>>>(
        X_bf, W_bf, b, (void*)G_bf, 2080, 512, 512);

    // main GEMM with fused A' construction: out[65536][2048]
    gemm256_8ph_fused<<<2048, 512, 0, stream>>>(G_bf, (float*)d_out);
}

// Round 4
// 238.196 us; speedup vs baseline: 1.2414x; 1.2414x over previous
//
#include <hip/hip_runtime.h>

typedef __attribute__((ext_vector_type(8))) __bf16 bf16x8;
typedef __attribute__((ext_vector_type(4))) float f32x4;

__device__ __forceinline__ float bf2f(unsigned int u) {
    return __uint_as_float(u << 16);
}
__device__ __forceinline__ unsigned short f2bf(float f) {
    unsigned int x = __float_as_uint(f);
    return (unsigned short)((x + 0x7fffu + ((x >> 16) & 1u)) >> 16);
}

// ---------------- merged cast f32 -> bf16 for entities+relations+W ----------------
// groups of 4 floats; [0,262144) -> X_bf (entities), [262144,266240) -> X_bf+2048*512
// (relations), [266240,331776) -> W_bf
__global__ void cast_all(const float* __restrict__ ent, const float* __restrict__ rel,
                         const float* __restrict__ W,
                         unsigned short* __restrict__ X_bf,
                         unsigned short* __restrict__ W_bf) {
    int i = blockIdx.x * blockDim.x + threadIdx.x;
    const float* src;
    unsigned short* dst;
    int g;
    if (i < 262144) {
        src = ent; dst = X_bf; g = i;
    } else if (i < 266240) {
        src = rel; dst = X_bf + 2048 * 512; g = i - 262144;
    } else {
        if (i >= 331776) return;
        src = W; dst = W_bf; g = i - 266240;
    }
    float4 v = reinterpret_cast<const float4*>(src)[g];
    ushort4 o;
    o.x = f2bf(v.x); o.y = f2bf(v.y); o.z = f2bf(v.z); o.w = f2bf(v.w);
    reinterpret_cast<ushort4*>(dst)[g] = o;
}

// ---------------- A'[(e*32+r), d] = E[e,d] * R[r,d] ----------------
__device__ __forceinline__ unsigned int mul2bf(unsigned int a, unsigned int b) {
    float a0 = bf2f(a & 0xffffu), a1 = bf2f(a >> 16);
    float b0 = bf2f(b & 0xffffu), b1 = bf2f(b >> 16);
    return (unsigned int)f2bf(a0 * b0) | ((unsigned int)f2bf(a1 * b1) << 16);
}

__global__ void build_ap(const unsigned short* __restrict__ G,
                         unsigned short* __restrict__ Ap) {
    int t = blockIdx.x * blockDim.x + threadIdx.x;
    int row = t >> 6;
    int d = (t & 63) * 8;
    int e = row >> 5, r = row & 31;
    const uint4 ev = *reinterpret_cast<const uint4*>(G + e * 512 + d);
    const uint4 rv = *reinterpret_cast<const uint4*>(G + (2048 + r) * 512 + d);
    uint4 o;
    o.x = mul2bf(ev.x, rv.x);
    o.y = mul2bf(ev.y, rv.y);
    o.z = mul2bf(ev.z, rv.z);
    o.w = mul2bf(ev.w, rv.w);
    *reinterpret_cast<uint4*>(Ap + (size_t)row * 512 + d) = o;
}

// ---------------- gate GEMM (m97 128^2 structure, known-good) ----------------
#define BM 128
#define BN 128
#define BK 64

template <bool GUARD_M, bool BIAS_BF16OUT>
__global__ __launch_bounds__(256, 2) void mfma_gemm_bt(
    const unsigned short* __restrict__ A,
    const unsigned short* __restrict__ Bt,
    const float* __restrict__ bias,
    void* __restrict__ Cout,
    int M, int N, int K) {
    __shared__ __align__(16) unsigned short As[BM * BK];
    __shared__ __align__(16) unsigned short Bs[BN * BK];

    const int tid = threadIdx.x;
    const int lane = tid & 63;
    const int wave = tid >> 6;
    const int nbn = N / BN;
    const int bm0 = (blockIdx.x / nbn) * BM;
    const int bn0 = (blockIdx.x % nbn) * BN;
    const int wr = wave >> 1, wc = wave & 1;

    f32x4 acc[4][4] = {};

    const int srow = wave * 32 + (lane >> 3);
    const int scol = (lane & 7) * 8;

    for (int kb = 0; kb < K; kb += BK) {
#pragma unroll
        for (int i = 0; i < 4; ++i) {
            int row = bm0 + srow + i * 8;
            if (GUARD_M) row = min(row, M - 1);
            const unsigned short* src = A + (size_t)row * K + kb + scol;
            unsigned short* dst = &As[(wave * 32 + i * 8) * BK];
            __builtin_amdgcn_global_load_lds(
                (const __attribute__((address_space(1))) void*)src,
                (__attribute__((address_space(3))) void*)dst, 16, 0, 0);
        }
#pragma unroll
        for (int i = 0; i < 4; ++i) {
            int row = bn0 + srow + i * 8;
            const unsigned short* src = Bt + (size_t)row * K + kb + scol;
            unsigned short* dst = &Bs[(wave * 32 + i * 8) * BK];
            __builtin_amdgcn_global_load_lds(
                (const __attribute__((address_space(1))) void*)src,
                (__attribute__((address_space(3))) void*)dst, 16, 0, 0);
        }
        __syncthreads();

#pragma unroll
        for (int ks = 0; ks < BK / 32; ++ks) {
            const int k0 = ks * 32 + (lane >> 4) * 8;
            bf16x8 av[4], bv[4];
#pragma unroll
            for (int m = 0; m < 4; ++m)
                av[m] = *reinterpret_cast<const bf16x8*>(
                    &As[(wr * 64 + m * 16 + (lane & 15)) * BK + k0]);
#pragma unroll
            for (int n = 0; n < 4; ++n)
                bv[n] = *reinterpret_cast<const bf16x8*>(
                    &Bs[(wc * 64 + n * 16 + (lane & 15)) * BK + k0]);
#pragma unroll
            for (int m = 0; m < 4; ++m)
#pragma unroll
                for (int n = 0; n < 4; ++n)
                    acc[m][n] = __builtin_amdgcn_mfma_f32_16x16x32_bf16(
                        av[m], bv[n], acc[m][n], 0, 0, 0);
        }
        __syncthreads();
    }

#pragma unroll
    for (int m = 0; m < 4; ++m) {
#pragma unroll
        for (int n = 0; n < 4; ++n) {
#pragma unroll
            for (int j = 0; j < 4; ++j) {
                int row = bm0 + wr * 64 + m * 16 + (lane >> 4) * 4 + j;
                int col = bn0 + wc * 64 + n * 16 + (lane & 15);
                if (GUARD_M && row >= M) continue;
                float v = acc[m][n][j];
                if (BIAS_BF16OUT) {
                    v += bias[col];
                    ((unsigned short*)Cout)[(size_t)row * N + col] = f2bf(v);
                } else {
                    ((float*)Cout)[(size_t)row * N + col] = v;
                }
            }
        }
    }
}

// ---------------- main GEMM: 256^2 tile, 8-phase, counted vmcnt ----------------
// C[65536][2048] = A'[65536][512] @ E[2048][512]^T
// LDS: 2 buffers x {A0,A1,B0,B1} half-tiles of 128rows x 64cols bf16 (16KB each)
// C stores are NON-TEMPORAL: write-once stream must not evict A'/B from L2/L3.
#define NT8 8  // K / 64

__global__ __launch_bounds__(512, 2) void gemm256_8ph(
    const unsigned short* __restrict__ A,  // [65536][512]
    const unsigned short* __restrict__ B,  // [2048][512] (= E rows of G)
    float* __restrict__ C) {
    __shared__ __align__(16) unsigned short lds[65536];  // 128 KiB

    const int tid = threadIdx.x;
    const int lane = tid & 63;
    const int wave = tid >> 6;   // 0..7
    const int wr = wave >> 2;    // 0..1 -> M half
    const int wc = wave & 3;     // 0..3 -> N quarter
    const int laneM = lane & 15;
    const int laneK = (lane >> 4) * 8;
    const int kx = (lane & 7) * 8;

    // XCD-aware swizzle (nwg=2048, divisible by 8); each dispatch-round of 256
    // blocks covers 32 bm0-tiles x all 8 bn0 -> A-tile HBM-fetched once/round.
    const int swz = (blockIdx.x & 7) * 256 + (blockIdx.x >> 3);
    const int bm0 = (swz >> 3) * 256;
    const int bn0 = (swz & 7) * 256;

    // staging coords: linear LDS dest, pre-swizzled global source (rule 21)
    const int sr0 = tid >> 3;                                   // row (+rd*64)
    const int sc = ((tid & 7) * 8) ^ (((tid >> 3) & 7) * 8);    // inverse-swizzled col

    auto STAGE = [&](const unsigned short* mat, int row0, int kb, int slotOff) {
#pragma unroll
        for (int rd = 0; rd < 2; ++rd) {
            const unsigned short* src = mat + (size_t)(row0 + sr0 + rd * 64) * 512 + kb + sc;
            unsigned short* dst = &lds[slotOff + wave * 512 + rd * 4096];  // wave-uniform
            __builtin_amdgcn_global_load_lds(
                (const __attribute__((address_space(1))) void*)src,
                (__attribute__((address_space(3))) void*)dst, 16, 0, 0);
        }
    };
    auto RD = [&](int slotOff, int r, int ks) -> bf16x8 {
        return *reinterpret_cast<const bf16x8*>(
            &lds[slotOff + r * 64 + (((ks * 32) + laneK) ^ kx)]);
    };
    // slots (ushort units): A(P,h)=P*32768+h*8192 ; B(P,h)=P*32768+16384+h*8192

    f32x4 acc[8][4] = {};
    bf16x8 av[4][2], bv0[2][2], bv1[2][2];

    // prologue: tile0 {A0,B0,B1,A1} + tile1 {B0,A0,B1}  (A1(1) staged at t0.ph1)
    STAGE(A, bm0,        0, 0 * 32768 + 0 * 8192);           // (0)A0
    STAGE(B, bn0,        0, 0 * 32768 + 16384 + 0 * 8192);   // (0)B0
    STAGE(B, bn0 + 128,  0, 0 * 32768 + 16384 + 1 * 8192);   // (0)B1
    STAGE(A, bm0 + 128,  0, 0 * 32768 + 1 * 8192);           // (0)A1
    STAGE(B, bn0,       64, 1 * 32768 + 16384 + 0 * 8192);   // (1)B0
    STAGE(A, bm0,       64, 1 * 32768 + 0 * 8192);           // (1)A0
    STAGE(B, bn0 + 128, 64, 1 * 32768 + 16384 + 1 * 8192);   // (1)B1
    asm volatile("s_waitcnt vmcnt(6)" ::: "memory");
    __builtin_amdgcn_s_barrier();

#pragma unroll
    for (int t = 0; t < NT8; ++t) {
        const int P = t & 1;
        const int sA = P * 32768 + wr * 8192;
        const int sB = P * 32768 + 16384 + (wc >> 1) * 8192;
        const int rB = (wc & 1) * 64;

        // ===== phase 1: read A-mh0 (8) + B-nh0 (4); stage (t+1)A1 =====
#pragma unroll
        for (int m = 0; m < 4; ++m)
#pragma unroll
            for (int ks = 0; ks < 2; ++ks)
                av[m][ks] = RD(sA, m * 16 + laneM, ks);
#pragma unroll
        for (int n = 0; n < 2; ++n)
#pragma unroll
            for (int ks = 0; ks < 2; ++ks)
                bv0[n][ks] = RD(sB, rB + n * 16 + laneM, ks);
        if (t + 1 < NT8)
            STAGE(A, bm0 + 128, (t + 1) * 64, ((t + 1) & 1) * 32768 + 8192);
        __builtin_amdgcn_s_barrier();
        asm volatile("s_waitcnt lgkmcnt(0)" ::: "memory");
        __builtin_amdgcn_sched_barrier(0);
        __builtin_amdgcn_s_setprio(1);
#pragma unroll
        for (int ks = 0; ks < 2; ++ks)
#pragma unroll
            for (int m = 0; m < 4; ++m)
#pragma unroll
                for (int n = 0; n < 2; ++n)
                    acc[m][n] = __builtin_amdgcn_mfma_f32_16x16x32_bf16(
                        av[m][ks], bv0[n][ks], acc[m][n], 0, 0, 0);
        __builtin_amdgcn_s_setprio(0);
        __builtin_amdgcn_s_barrier();

        // ===== phase 2: read B-nh1 (4) =====
#pragma unroll
        for (int n = 0; n < 2; ++n)
#pragma unroll
            for (int ks = 0; ks < 2; ++ks)
                bv1[n][ks] = RD(sB, rB + (2 + n) * 16 + laneM, ks);
        __builtin_amdgcn_s_barrier();
        asm volatile("s_waitcnt lgkmcnt(0)" ::: "memory");
        __builtin_amdgcn_sched_barrier(0);
        __builtin_amdgcn_s_setprio(1);
#pragma unroll
        for (int ks = 0; ks < 2; ++ks)
#pragma unroll
            for (int m = 0; m < 4; ++m)
#pragma unroll
                for (int n = 0; n < 2; ++n)
                    acc[m][2 + n] = __builtin_amdgcn_mfma_f32_16x16x32_bf16(
                        av[m][ks], bv1[n][ks], acc[m][2 + n], 0, 0, 0);
        __builtin_amdgcn_s_setprio(0);
        __builtin_amdgcn_s_barrier();

        // ===== phase 3: read A-mh1 (8); stage (t+2)B0 =====
#pragma unroll
        for (int m = 0; m < 4; ++m)
#pragma unroll
            for (int ks = 0; ks < 2; ++ks)
                av[m][ks] = RD(sA, 64 + m * 16 + laneM, ks);
        if (t + 2 < NT8)
            STAGE(B, bn0, (t + 2) * 64, ((t + 2) & 1) * 32768 + 16384);
        __builtin_amdgcn_s_barrier();
        asm volatile("s_waitcnt lgkmcnt(0)" ::: "memory");
        __builtin_amdgcn_sched_barrier(0);
        __builtin_amdgcn_s_setprio(1);
#pragma unroll
        for (int ks = 0; ks < 2; ++ks)
#pragma unroll
            for (int m = 0; m < 4; ++m)
#pragma unroll
                for (int n = 0; n < 2; ++n)
                    acc[4 + m][2 + n] = __builtin_amdgcn_mfma_f32_16x16x32_bf16(
                        av[m][ks], bv1[n][ks], acc[4 + m][2 + n], 0, 0, 0);
        __builtin_amdgcn_s_setprio(0);
        __builtin_amdgcn_s_barrier();

        // ===== phase 4: stage (t+2)A0 + (t+2)B1; MFMA Q10 from regs =====
        if (t + 2 < NT8) {
            STAGE(A, bm0, (t + 2) * 64, ((t + 2) & 1) * 32768);
            STAGE(B, bn0 + 128, (t + 2) * 64, ((t + 2) & 1) * 32768 + 16384 + 8192);
        }
        __builtin_amdgcn_s_barrier();
        __builtin_amdgcn_s_setprio(1);
#pragma unroll
        for (int ks = 0; ks < 2; ++ks)
#pragma unroll
            for (int m = 0; m < 4; ++m)
#pragma unroll
                for (int n = 0; n < 2; ++n)
                    acc[4 + m][n] = __builtin_amdgcn_mfma_f32_16x16x32_bf16(
                        av[m][ks], bv0[n][ks], acc[4 + m][n], 0, 0, 0);
        __builtin_amdgcn_s_setprio(0);
        if (t < NT8 - 1) {
            if (t == NT8 - 2)
                asm volatile("s_waitcnt vmcnt(0)" ::: "memory");
            else
                asm volatile("s_waitcnt vmcnt(6)" ::: "memory");
            __builtin_amdgcn_s_barrier();
        }
    }

    // epilogue: C/D layout col=lane&15, row=(lane>>4)*4+j ; non-temporal stores
#pragma unroll
    for (int mi = 0; mi < 8; ++mi)
#pragma unroll
        for (int ni = 0; ni < 4; ++ni)
#pragma unroll
            for (int j = 0; j < 4; ++j) {
                int row = bm0 + wr * 128 + mi * 16 + (lane >> 4) * 4 + j;
                int col = bn0 + wc * 64 + ni * 16 + laneM;
                __builtin_nontemporal_store(acc[mi][ni][j],
                                            &C[(size_t)row * 2048 + col]);
            }
}

// ---------------- launcher ----------------
extern "C" void kernel_launch(void* const* d_in, const int* in_sizes, int n_in,
                              void* d_out, int out_size, void* d_ws, size_t ws_size,
                              hipStream_t stream) {
    const float* entities  = (const float*)d_in[0];
    const float* relations = (const float*)d_in[1];
    const float* W         = (const float*)d_in[2];
    const float* b         = (const float*)d_in[3];

    char* ws = (char*)d_ws;
    unsigned short* W_bf = (unsigned short*)ws;
    unsigned short* X_bf = (unsigned short*)(ws + 524288);
    unsigned short* G_bf = (unsigned short*)(ws + 524288 + 2129920);
    unsigned short* Ap   = (unsigned short*)(ws + 524288 + 2129920 + 2129920);

    cast_all<<<1296, 256, 0, stream>>>(entities, relations, W, X_bf, W_bf);

    // gate GEMM: G[2080][512] = X @ W^T + b  (bf16 out)
    mfma_gemm_bt<true, true><<<17 * 4, 256, 0, stream>>>(
        X_bf, W_bf, b, (void*)G_bf, 2080, 512, 512);

    // A'[(e*32+r), d] = E[e,d] * R[r,d]
    build_ap<<<16384, 256, 0, stream>>>(G_bf, Ap);

    // main GEMM: out[65536][2048] = A' @ E^T
    gemm256_8ph<<<2048, 512, 0, stream>>>(Ap, G_bf, (float*)d_out);
}